// Round 1
// baseline (452.823 us; speedup 1.0000x reference)
//
#include <hip/hip_runtime.h>

// CrossAttention decode, algebraically collapsed (all fp32):
//   q[b,h,:]   = ((x1@We1+be1)@Wq+bq) head-sliced
//   u[b,h,c]   = sum_d WkT[h*64+d,c]*q[b,h,d]
//   w[b,h,i]   = sum_c u[b,h,c]*We2t[c,i]          (K-proj folded)
//   score[b,h,s] = x2[b,s,:].w[b,h,:]              (K-bias cancels in softmax)
//   a = softmax(score/8)
//   g[b,h,i]   = sum_s a[b,h,s]*x3[b,s,i]
//   G2[b,h,c]  = g@We2 + be2;  av = G2@Wv_h + bv;  out = av@Wo + bo
// R1 (this round): k_attn was latency-bound (Occ 21%, VALUBusy 23%, HBM 16%)
// at 2 blocks/CU with ~27 barriers/block. Restructured: NCH=64 (1024 blocks,
// 4/CU, 50% occ cap), phase B decomposed as wave=own-4-heads x all-64-rows
// (same head split as phase A) -> scores never leave registers (shfl-xor
// chunk max), exp count 512->4/thread via per-wave e-table aliasing the dead
// x2 tile, cross-wave combine DELETED (wave writes its gp rows directly),
// zero barriers after the kt loop, 2-deep pipelined x3 reads. x3 is read 4x
// per block but 3x are L1/L2 hits (128KB tile << 4MB L2); HBM fetch same.
// Lessons kept: no per-element global atomics on hot paths (R4); stride-33
// float4 LDS tiles (conflict-free, SQ_LDS_BANK_CONFLICT ~0.5/read); harness
// reset (~170us) is fixed overhead inside the timing window.

#define DIN 512
#define DD  1024
#define NH  16
#define HD  64
#define BB  16
#define SS  4096
#define NCH 64   // s-chunks; schunk = 64

__device__ __forceinline__ int wave_id() {
    return __builtin_amdgcn_readfirstlane((int)(threadIdx.x >> 6));
}

__device__ __forceinline__ void tile_transpose(const float* __restrict__ in,
                                               float* __restrict__ out,
                                               int R, int C, int rblk, int cblk) {
    __shared__ float tl[32][33];
    const int tx = threadIdx.x & 31, ty = threadIdx.x >> 5;  // ty 0..7
    const int c0 = cblk * 32, r0 = rblk * 32;
#pragma unroll
    for (int k = 0; k < 4; ++k)
        tl[ty + k * 8][tx] = in[(size_t)(r0 + ty + k * 8) * C + c0 + tx];
    __syncthreads();
#pragma unroll
    for (int k = 0; k < 4; ++k)
        out[(size_t)(c0 + ty + k * 8) * R + r0 + tx] = tl[tx][ty + k * 8];
}

// One fused prep dispatch: We2/Wk transposes + bias init of atomic targets.
__global__ __launch_bounds__(256) void k_prep(const float* __restrict__ We2,
                                              const float* __restrict__ Wk,
                                              const float* __restrict__ be1,
                                              const float* __restrict__ bq,
                                              const float* __restrict__ bv,
                                              const float* __restrict__ bo,
                                              float* __restrict__ We2t,
                                              float* __restrict__ WkT,
                                              float* __restrict__ x1e,
                                              float* __restrict__ qb,
                                              float* __restrict__ av,
                                              float* __restrict__ out) {
    const int bx = blockIdx.x;
    if (bx < 512) {
        tile_transpose(We2, We2t, DIN, DD, bx >> 5, bx & 31);
    } else if (bx < 1536) {
        const int lb = bx - 512;
        tile_transpose(Wk, WkT, DD, DD, lb >> 5, lb & 31);
    } else {
        const int b = bx - 1536;
#pragma unroll
        for (int k = 0; k < 4; ++k) {
            const int c = k * 256 + threadIdx.x;
            x1e[(size_t)b * DD + c] = be1[c];
            qb[(size_t)b * DD + c]  = bq[c];
            av[(size_t)b * DD + c]  = bv[c];
            out[(size_t)b * DD + c] = bo[c];
        }
    }
}

// out[r][c] (+)= sum_i in[r][i]*W[i][c] for 16 rows. grid (N/64, R/16, KS).
template <int K, int N, int KS, bool HASB>
__global__ __launch_bounds__(256) void k_bmv2(const float* __restrict__ in,
                                              const float* __restrict__ W,
                                              const float* __restrict__ bias,
                                              float* __restrict__ out) {
    const int l = threadIdx.x & 63;
    const int c = blockIdx.x * 64 + l;
    const int wv = wave_id();
    constexpr int KCH = K / KS;
    constexpr int SUB = KCH / 4;
    const float* inb = in + (size_t)blockIdx.y * 16 * K;  // uniform -> s_load
    float acc[16];
#pragma unroll
    for (int r = 0; r < 16; ++r) acc[r] = 0.f;
    const int i0 = blockIdx.z * KCH + wv * SUB;
#pragma unroll 4
    for (int i = i0; i < i0 + SUB; ++i) {
        const float wval = W[(size_t)i * N + c];  // coalesced 256B/wave
#pragma unroll
        for (int r = 0; r < 16; ++r) acc[r] += inb[(size_t)r * K + i] * wval;
    }
    __shared__ float red[4][16][64];
#pragma unroll
    for (int r = 0; r < 16; ++r) red[wv][r][l] = acc[r];
    __syncthreads();
#pragma unroll
    for (int k = 0; k < 4; ++k) {
        const int r = wv + k * 4;
        float v = red[0][r][l] + red[1][r][l] + red[2][r][l] + red[3][r][l];
        float* dst = out + ((size_t)blockIdx.y * 16 + r) * N + c;
        if (KS == 1) {
            if (HASB) v += bias[c];
            *dst = v;
        } else {
            atomicAdd(dst, v);
        }
    }
}

// u[b*16+h][c] = sum_d q[b][h*64+d]*WkT[h*64+d][c].  grid (1024/64, 16 h).
__global__ __launch_bounds__(256) void k_u2(const float* __restrict__ q,
                                            const float* __restrict__ WkT,
                                            float* __restrict__ u) {
    const int h = blockIdx.y;
    const int l = threadIdx.x & 63;
    const int c = blockIdx.x * 64 + l;
    const int wv = wave_id();
    float acc[16];
#pragma unroll
    for (int bb = 0; bb < 16; ++bb) acc[bb] = 0.f;
#pragma unroll 4
    for (int dk = 0; dk < 16; ++dk) {
        const int d = wv * 16 + dk;
        const float wval = WkT[(size_t)(h * HD + d) * DD + c];  // coalesced
#pragma unroll
        for (int bb = 0; bb < 16; ++bb)
            acc[bb] += q[(size_t)bb * DD + h * HD + d] * wval;  // s_load
    }
    __shared__ float red[4][16][64];
#pragma unroll
    for (int bb = 0; bb < 16; ++bb) red[wv][bb][l] = acc[bb];
    __syncthreads();
#pragma unroll
    for (int k = 0; k < 4; ++k) {
        const int bb = wv + k * 4;
        float v = red[0][bb][l] + red[1][bb][l] + red[2][bb][l] + red[3][bb][l];
        u[((size_t)bb * NH + h) * DD + c] = v;
    }
}

// Fused scores+softmax+PV: grid (NCH=64, 16 b), block 256 (4 waves).
// Phase A: wave wv owns heads h0..h0+3, lane = s-row; x2 staged in stride-33
// float4 LDS, scores accumulate in registers across 4 kt passes.
// Then: per-head chunk max via 6-step shfl_xor butterfly (no LDS), e-values
// exp'd once per lane into a per-wave e-table (aliases the dead x2 tile).
// Phase B: same wave keeps its 4 heads, iterates ALL 64 rows of x3 (2-deep
// pipelined float4 loads; repeats across waves hit L1/L2), accumulates
// acc[4][8]; writes its gp rows + (m,l) directly. No cross-wave combine.
__global__ __launch_bounds__(256, 4) void k_attn(const float* __restrict__ x2,
                                                 const float* __restrict__ x3,
                                                 const float* __restrict__ w,
                                                 float* __restrict__ gp,
                                                 float* __restrict__ mls) {
    __shared__ __align__(16) float4 tile[64 * 33];  // 33.8 KB x2 stage
    float* etab = (float*)tile;                     // [wv][j=64][hh=4], 4 KB, phase-B alias

    const int b = blockIdx.y, ch = blockIdx.x;
    const int l = threadIdx.x & 63;
    const int wv = wave_id();
    const int h0 = wv * 4;
    const int s0 = ch * 64;
    const float4* wp = (const float4*)(w + ((size_t)b * NH + h0) * DIN);
    const float4* x2f = (const float4*)x2 + ((size_t)b * SS + s0) * (DIN / 4);

    // ---- phase A: scores for rows s0..s0+64, heads h0..h0+3 (lane = row) ----
    float a0 = 0.f, a1 = 0.f, a2 = 0.f, a3 = 0.f;
    for (int kt = 0; kt < 4; ++kt) {
#pragma unroll
        for (int k = 0; k < 8; ++k) {
            const int idx = threadIdx.x + k * 256;
            const int row = idx >> 5, c4 = idx & 31;
            tile[row * 33 + c4] = x2f[(size_t)row * 128 + kt * 32 + c4];
        }
        __syncthreads();
#pragma unroll 8
        for (int c4 = 0; c4 < 32; ++c4) {
            const float4 x = tile[l * 33 + c4];
            const float4 q0 = wp[kt * 32 + c4];            // uniform -> s_load
            const float4 q1 = wp[128 + kt * 32 + c4];
            const float4 q2 = wp[256 + kt * 32 + c4];
            const float4 q3 = wp[384 + kt * 32 + c4];
            a0 += x.x * q0.x + x.y * q0.y + x.z * q0.z + x.w * q0.w;
            a1 += x.x * q1.x + x.y * q1.y + x.z * q1.z + x.w * q1.w;
            a2 += x.x * q2.x + x.y * q2.y + x.z * q2.z + x.w * q2.w;
            a3 += x.x * q3.x + x.y * q3.y + x.z * q3.z + x.w * q3.w;
        }
        __syncthreads();   // all waves done reading tile -> safe to overwrite
    }

    // scaled scores for this lane's row; per-head max over all 64 rows
    const float sc0 = a0 * 0.125f, sc1 = a1 * 0.125f;
    const float sc2 = a2 * 0.125f, sc3 = a3 * 0.125f;
    float mh[4] = {sc0, sc1, sc2, sc3};
#pragma unroll
    for (int k = 0; k < 4; ++k) {
#pragma unroll
        for (int off = 1; off < 64; off <<= 1)
            mh[k] = fmaxf(mh[k], __shfl_xor(mh[k], off));
    }

    // e-table: lane l holds row l's e for the wave's 4 heads (tile is dead)
    const float4 ev = make_float4(__expf(sc0 - mh[0]), __expf(sc1 - mh[1]),
                                  __expf(sc2 - mh[2]), __expf(sc3 - mh[3]));
    *(float4*)&etab[(wv * 64 + l) * 4] = ev;

    // ---- phase B: wave accumulates its 4 heads over all 64 x3 rows ----
    const float4* xr = (const float4*)(x3 + ((size_t)b * SS + s0) * DIN);
    float acc[4][8];
#pragma unroll
    for (int k = 0; k < 4; ++k)
#pragma unroll
        for (int jj = 0; jj < 8; ++jj) acc[k][jj] = 0.f;
    float ls[4] = {0.f, 0.f, 0.f, 0.f};

    float4 pa = xr[l], pb = xr[64 + l];          // row 0
    float4 na = xr[128 + l], nb = xr[192 + l];   // row 1
#pragma unroll 4
    for (int j = 0; j < 64; ++j) {
        const float4 xa = pa, xb = pb;
        pa = na; pb = nb;
        const int jn = (j + 2 < 64) ? (j + 2) : 63;
        na = xr[(size_t)jn * 128 + l];
        nb = xr[(size_t)jn * 128 + 64 + l];
        const float4 e4 = *(const float4*)&etab[(wv * 64 + j) * 4];  // broadcast
        const float ee[4] = {e4.x, e4.y, e4.z, e4.w};
        const float xv[8] = {xa.x, xa.y, xa.z, xa.w, xb.x, xb.y, xb.z, xb.w};
#pragma unroll
        for (int k = 0; k < 4; ++k) {
            ls[k] += ee[k];
#pragma unroll
            for (int jj = 0; jj < 8; ++jj) acc[k][jj] += ee[k] * xv[jj];
        }
    }

    // epilogue: per-wave direct gp + (m,l) writes; no block combine
    float* gb = gp + ((size_t)(b * NCH + ch) * NH + h0) * DIN;
#pragma unroll
    for (int k = 0; k < 4; ++k) {
        *(float4*)(gb + (size_t)k * DIN + 4 * l) =
            make_float4(acc[k][0], acc[k][1], acc[k][2], acc[k][3]);
        *(float4*)(gb + (size_t)k * DIN + 256 + 4 * l) =
            make_float4(acc[k][4], acc[k][5], acc[k][6], acc[k][7]);
    }
    if (l == 0) {
#pragma unroll
        for (int k = 0; k < 4; ++k) {
            float* dst = mls + (((size_t)b * NCH + ch) * NH + h0 + k) * 2;
            dst[0] = mh[k];
            dst[1] = ls[k];
        }
    }
}

// Flash combine: g[b*16+h][i] = sum_ch exp(m_ch-M)*gp_ch[i] / sum_ch exp(m_ch-M)*l_ch
// grid 512: blockIdx.x = pair*2 + half; thread owns one i-col.
__global__ __launch_bounds__(256) void k_greduce2(const float* __restrict__ gp,
                                                  const float* __restrict__ mls,
                                                  float* __restrict__ g) {
    const int bx = blockIdx.x;        // 512
    const int pair = bx >> 1;         // b*16+h
    const int b = pair >> 4, h = pair & 15;
    const int i = (bx & 1) * 256 + threadIdx.x;
    const float* mbase = mls + ((size_t)b * NCH * NH + h) * 2;  // stride NH*2/ch
    float M = -1e30f;
#pragma unroll 8
    for (int ch = 0; ch < NCH; ++ch)
        M = fmaxf(M, mbase[(size_t)ch * NH * 2]);   // uniform -> s_load
    float L = 0.f;
#pragma unroll 8
    for (int ch = 0; ch < NCH; ++ch)
        L += __expf(mbase[(size_t)ch * NH * 2] - M) * mbase[(size_t)ch * NH * 2 + 1];
    const float invL = 1.f / L;
    const float* gpb = gp + ((size_t)(b * NCH) * NH + h) * DIN + i;
    float acc = 0.f;
#pragma unroll 8
    for (int ch = 0; ch < NCH; ++ch)
        acc += __expf(mbase[(size_t)ch * NH * 2] - M) * gpb[(size_t)ch * NH * DIN];
    g[(size_t)pair * DIN + i] = acc * invL;
}

// av[b][h*64+l] (+)= sum_c G2[b*16+h][c]*Wv[c][h*64+l] over a 128-c chunk.
__global__ __launch_bounds__(256) void k_av_at(const float* __restrict__ G2,
                                               const float* __restrict__ Wv,
                                               float* __restrict__ av) {
    const int h = blockIdx.x;
    const int l = threadIdx.x & 63;
    const int wv = wave_id();
    const int c0 = blockIdx.y * 128 + wv * 32;
    float acc[16];
#pragma unroll
    for (int bb = 0; bb < 16; ++bb) acc[bb] = 0.f;
#pragma unroll 4
    for (int c = c0; c < c0 + 32; ++c) {
        const float wval = Wv[(size_t)c * DD + h * HD + l];  // coalesced
#pragma unroll
        for (int bb = 0; bb < 16; ++bb)
            acc[bb] += G2[((size_t)bb * NH + h) * DD + c] * wval;  // s_load
    }
    __shared__ float red[4][16][64];
#pragma unroll
    for (int bb = 0; bb < 16; ++bb) red[wv][bb][l] = acc[bb];
    __syncthreads();
#pragma unroll
    for (int k = 0; k < 4; ++k) {
        const int bb = wv + k * 4;
        float v = red[0][bb][l] + red[1][bb][l] + red[2][bb][l] + red[3][bb][l];
        atomicAdd(&av[(size_t)bb * DD + h * HD + l], v);
    }
}

extern "C" void kernel_launch(void* const* d_in, const int* in_sizes, int n_in,
                              void* d_out, int out_size, void* d_ws, size_t ws_size,
                              hipStream_t stream) {
    const float* x1  = (const float*)d_in[0];
    const float* x2  = (const float*)d_in[1];
    const float* x3  = (const float*)d_in[2];
    const float* We1 = (const float*)d_in[3];
    const float* be1 = (const float*)d_in[4];
    const float* We2 = (const float*)d_in[5];
    const float* be2 = (const float*)d_in[6];
    const float* Wq  = (const float*)d_in[7];
    const float* bq  = (const float*)d_in[8];
    const float* Wk  = (const float*)d_in[9];
    const float* bk  = (const float*)d_in[10];  // cancels in softmax (unused)
    const float* Wv  = (const float*)d_in[11];
    const float* bv  = (const float*)d_in[12];
    const float* Wo  = (const float*)d_in[13];
    const float* bo  = (const float*)d_in[14];
    (void)bk;
    float* out = (float*)d_out;

    char* ws = (char*)d_ws;
    size_t off = 0;
    auto alloc = [&](size_t bytes) -> void* {
        void* p = ws + off;
        off = (off + bytes + 255) & ~(size_t)255;
        return p;
    };
    float* We2t = (float*)alloc((size_t)DD * DIN * 4);  // [1024][512]
    float* WkT  = (float*)alloc((size_t)DD * DD * 4);   // [1024][1024]
    float* x1e  = (float*)alloc((size_t)BB * DD * 4);
    float* qb   = (float*)alloc((size_t)BB * DD * 4);
    float* u    = (float*)alloc((size_t)BB * NH * DD * 4);
    float* wv_  = (float*)alloc((size_t)BB * NH * DIN * 4);
    float* g    = (float*)alloc((size_t)BB * NH * DIN * 4);
    float* G2   = (float*)alloc((size_t)BB * NH * DD * 4);
    float* av   = (float*)alloc((size_t)BB * DD * 4);
    float* gp   = (float*)alloc((size_t)BB * NCH * NH * DIN * 4);  // 32MB
    float* mls  = (float*)alloc((size_t)BB * NCH * NH * 2 * 4);

    // prep: transposes + bias inits (one dispatch)
    k_prep<<<1552, 256, 0, stream>>>(We2, Wk, be1, bq, bv, bo,
                                     We2t, WkT, x1e, qb, av, out);
    // x1e += x1@We1   (K=512, KS=8 -> 128 blocks)
    k_bmv2<DIN, DD, 8, false><<<dim3(DD / 64, 1, 8), 256, 0, stream>>>(x1, We1, nullptr, x1e);
    // qb += x1e@Wq    (K=1024, KS=8 -> 128 blocks)
    k_bmv2<DD, DD, 8, false><<<dim3(DD / 64, 1, 8), 256, 0, stream>>>(x1e, Wq, nullptr, qb);
    k_u2<<<dim3(DD / 64, NH), 256, 0, stream>>>(qb, WkT, u);
    // w = u@We2t      (R=256 -> 128 blocks)
    k_bmv2<DD, DIN, 1, false><<<dim3(DIN / 64, BB * NH / 16, 1), 256, 0, stream>>>(u, We2t, nullptr, wv_);
    // fused scores + softmax + PV partials (1024 blocks, 4/CU)
    k_attn<<<dim3(NCH, BB), 256, 0, stream>>>(x2, x3, wv_, gp, mls);
    k_greduce2<<<BB * NH * 2, 256, 0, stream>>>(gp, mls, g);
    // G2 = g@We2+be2  (R=256 -> 256 blocks)
    k_bmv2<DIN, DD, 1, true><<<dim3(DD / 64, BB * NH / 16, 1), 256, 0, stream>>>(g, We2, be2, G2);
    k_av_at<<<dim3(NH, 8), 256, 0, stream>>>(G2, Wv, av);
    // out += av@Wo    (K=1024, KS=8 -> 128 blocks)
    k_bmv2<DD, DD, 8, false><<<dim3(DD / 64, 1, 8), 256, 0, stream>>>(av, Wo, nullptr, out);
}

// Round 2
// 446.875 us; speedup vs baseline: 1.0133x; 1.0133x over previous
//
#include <hip/hip_runtime.h>

// CrossAttention decode, algebraically collapsed (all fp32):
//   q[b,h,:]   = ((x1@We1+be1)@Wq+bq) head-sliced
//   u[b,h,c]   = sum_d WkT[h*64+d,c]*q[b,h,d]
//   w[b,h,i]   = sum_c u[b,h,c]*We2t[c,i]          (K-proj folded)
//   score[b,h,s] = x2[b,s,:].w[b,h,:]              (K-bias cancels in softmax)
//   a = softmax(score/8)
//   g[b,h,i]   = sum_s a[b,h,s]*x3[b,s,i]
//   G2[b,h,c]  = g@We2 + be2;  av = G2@Wv_h + bv;  out = av@Wo + bo
// R2 (this round): R1 raised blocks/CU capacity to 4 but the grid is exactly
// 1024 blocks = 4/CU, so occupancy capped at 16 waves/CU (measured 39%).
// k_attn now uses 512-thread blocks (8 waves): 8192 waves = 32/CU = 100% cap,
// zero grid tail. Phase A: wave owns 2 heads, lane = s-row, same stride-33
// tile (33.8KB) + separate 5KB padded e-table = 38.9KB (fits 4 blocks/CU).
// Softmax max AND sum now both per-wave shfl-xor reductions in phase A.
// Phase B re-decomposed: wave = 64-col slice, lane = 1 col, all 64 rows x
// all 16 heads (acc[16]); e read as 4 aligned broadcast float4 from the
// shared e-table. x3 re-read eliminated (cols partitioned across waves ->
// each x3 element read exactly once per block); 4-deep scalar pipeline.
// Lessons kept: no per-element global atomics on hot paths; stride-33/pad-20
// LDS (conflict-free, measured 0); harness reset (~170us) is fixed overhead.

#define DIN 512
#define DD  1024
#define NH  16
#define HD  64
#define BB  16
#define SS  4096
#define NCH 64   // s-chunks; schunk = 64

__device__ __forceinline__ int wave_id() {
    return __builtin_amdgcn_readfirstlane((int)(threadIdx.x >> 6));
}

__device__ __forceinline__ void tile_transpose(const float* __restrict__ in,
                                               float* __restrict__ out,
                                               int R, int C, int rblk, int cblk) {
    __shared__ float tl[32][33];
    const int tx = threadIdx.x & 31, ty = threadIdx.x >> 5;  // ty 0..7
    const int c0 = cblk * 32, r0 = rblk * 32;
#pragma unroll
    for (int k = 0; k < 4; ++k)
        tl[ty + k * 8][tx] = in[(size_t)(r0 + ty + k * 8) * C + c0 + tx];
    __syncthreads();
#pragma unroll
    for (int k = 0; k < 4; ++k)
        out[(size_t)(c0 + ty + k * 8) * R + r0 + tx] = tl[tx][ty + k * 8];
}

// One fused prep dispatch: We2/Wk transposes + bias init of atomic targets.
__global__ __launch_bounds__(256) void k_prep(const float* __restrict__ We2,
                                              const float* __restrict__ Wk,
                                              const float* __restrict__ be1,
                                              const float* __restrict__ bq,
                                              const float* __restrict__ bv,
                                              const float* __restrict__ bo,
                                              float* __restrict__ We2t,
                                              float* __restrict__ WkT,
                                              float* __restrict__ x1e,
                                              float* __restrict__ qb,
                                              float* __restrict__ av,
                                              float* __restrict__ out) {
    const int bx = blockIdx.x;
    if (bx < 512) {
        tile_transpose(We2, We2t, DIN, DD, bx >> 5, bx & 31);
    } else if (bx < 1536) {
        const int lb = bx - 512;
        tile_transpose(Wk, WkT, DD, DD, lb >> 5, lb & 31);
    } else {
        const int b = bx - 1536;
#pragma unroll
        for (int k = 0; k < 4; ++k) {
            const int c = k * 256 + threadIdx.x;
            x1e[(size_t)b * DD + c] = be1[c];
            qb[(size_t)b * DD + c]  = bq[c];
            av[(size_t)b * DD + c]  = bv[c];
            out[(size_t)b * DD + c] = bo[c];
        }
    }
}

// out[r][c] (+)= sum_i in[r][i]*W[i][c] for 16 rows. grid (N/64, R/16, KS).
template <int K, int N, int KS, bool HASB>
__global__ __launch_bounds__(256) void k_bmv2(const float* __restrict__ in,
                                              const float* __restrict__ W,
                                              const float* __restrict__ bias,
                                              float* __restrict__ out) {
    const int l = threadIdx.x & 63;
    const int c = blockIdx.x * 64 + l;
    const int wv = wave_id();
    constexpr int KCH = K / KS;
    constexpr int SUB = KCH / 4;
    const float* inb = in + (size_t)blockIdx.y * 16 * K;  // uniform -> s_load
    float acc[16];
#pragma unroll
    for (int r = 0; r < 16; ++r) acc[r] = 0.f;
    const int i0 = blockIdx.z * KCH + wv * SUB;
#pragma unroll 4
    for (int i = i0; i < i0 + SUB; ++i) {
        const float wval = W[(size_t)i * N + c];  // coalesced 256B/wave
#pragma unroll
        for (int r = 0; r < 16; ++r) acc[r] += inb[(size_t)r * K + i] * wval;
    }
    __shared__ float red[4][16][64];
#pragma unroll
    for (int r = 0; r < 16; ++r) red[wv][r][l] = acc[r];
    __syncthreads();
#pragma unroll
    for (int k = 0; k < 4; ++k) {
        const int r = wv + k * 4;
        float v = red[0][r][l] + red[1][r][l] + red[2][r][l] + red[3][r][l];
        float* dst = out + ((size_t)blockIdx.y * 16 + r) * N + c;
        if (KS == 1) {
            if (HASB) v += bias[c];
            *dst = v;
        } else {
            atomicAdd(dst, v);
        }
    }
}

// u[b*16+h][c] = sum_d q[b][h*64+d]*WkT[h*64+d][c].  grid (1024/64, 16 h).
__global__ __launch_bounds__(256) void k_u2(const float* __restrict__ q,
                                            const float* __restrict__ WkT,
                                            float* __restrict__ u) {
    const int h = blockIdx.y;
    const int l = threadIdx.x & 63;
    const int c = blockIdx.x * 64 + l;
    const int wv = wave_id();
    float acc[16];
#pragma unroll
    for (int bb = 0; bb < 16; ++bb) acc[bb] = 0.f;
#pragma unroll 4
    for (int dk = 0; dk < 16; ++dk) {
        const int d = wv * 16 + dk;
        const float wval = WkT[(size_t)(h * HD + d) * DD + c];  // coalesced
#pragma unroll
        for (int bb = 0; bb < 16; ++bb)
            acc[bb] += q[(size_t)bb * DD + h * HD + d] * wval;  // s_load
    }
    __shared__ float red[4][16][64];
#pragma unroll
    for (int bb = 0; bb < 16; ++bb) red[wv][bb][l] = acc[bb];
    __syncthreads();
#pragma unroll
    for (int k = 0; k < 4; ++k) {
        const int bb = wv + k * 4;
        float v = red[0][bb][l] + red[1][bb][l] + red[2][bb][l] + red[3][bb][l];
        u[((size_t)bb * NH + h) * DD + c] = v;
    }
}

// Fused scores+softmax+PV: grid (NCH=64, 16 b), block 512 (8 waves).
// Phase A: wave wv owns heads 2wv..2wv+1, lane = s-row; x2 staged in
// stride-33 float4 LDS; per-head chunk max AND sum via shfl-xor butterflies;
// e-values written to a pad-20 e-table [row][head]; mls written here.
// Phase B: wave wv owns cols [wv*64, +64), lane = 1 col; iterates all 64
// rows x all 16 heads (acc[16]); e read as 4 broadcast float4/row; x3 read
// exactly once per block (cols partitioned); 4-deep scalar load pipeline.
__global__ __launch_bounds__(512, 8) void k_attn(const float* __restrict__ x2,
                                                 const float* __restrict__ x3,
                                                 const float* __restrict__ w,
                                                 float* __restrict__ gp,
                                                 float* __restrict__ mls) {
    __shared__ __align__(16) float4 tile[64 * 33];  // 33.8 KB x2 stage
    __shared__ __align__(16) float etab[64 * 20];   // 5 KB e-table [row][head], pad 20

    const int b = blockIdx.y, ch = blockIdx.x;
    const int l = threadIdx.x & 63;
    const int wv = wave_id();          // 0..7
    const int h0 = wv * 2;
    const int s0 = ch * 64;
    const float4* wp = (const float4*)(w + ((size_t)b * NH + h0) * DIN);
    const float4* x2f = (const float4*)x2 + ((size_t)b * SS + s0) * (DIN / 4);

    // ---- phase A: scores for rows s0..s0+64, heads h0..h0+1 (lane = row) ----
    float a0 = 0.f, a1 = 0.f;
    for (int kt = 0; kt < 4; ++kt) {
#pragma unroll
        for (int k = 0; k < 4; ++k) {
            const int idx = threadIdx.x + k * 512;
            const int row = idx >> 5, c4 = idx & 31;
            tile[row * 33 + c4] = x2f[(size_t)row * 128 + kt * 32 + c4];
        }
        __syncthreads();
#pragma unroll 8
        for (int c4 = 0; c4 < 32; ++c4) {
            const float4 x = tile[l * 33 + c4];
            const float4 q0 = wp[kt * 32 + c4];            // uniform -> s_load
            const float4 q1 = wp[128 + kt * 32 + c4];
            a0 += x.x * q0.x + x.y * q0.y + x.z * q0.z + x.w * q0.w;
            a1 += x.x * q1.x + x.y * q1.y + x.z * q1.z + x.w * q1.w;
        }
        __syncthreads();   // all waves done reading tile -> safe to overwrite
    }

    // per-head chunk max + e + sum, all in-wave (lane = row)
    const float sc0 = a0 * 0.125f, sc1 = a1 * 0.125f;
    float m0 = sc0, m1 = sc1;
#pragma unroll
    for (int off = 1; off < 64; off <<= 1) {
        m0 = fmaxf(m0, __shfl_xor(m0, off));
        m1 = fmaxf(m1, __shfl_xor(m1, off));
    }
    const float e0 = __expf(sc0 - m0), e1 = __expf(sc1 - m1);
    etab[l * 20 + h0]     = e0;
    etab[l * 20 + h0 + 1] = e1;
    float ls0 = e0, ls1 = e1;
#pragma unroll
    for (int off = 1; off < 64; off <<= 1) {
        ls0 += __shfl_xor(ls0, off);
        ls1 += __shfl_xor(ls1, off);
    }
    if (l == 0) {
        float* dst = mls + (((size_t)b * NCH + ch) * NH + h0) * 2;
        dst[0] = m0; dst[1] = ls0;
        dst[2] = m1; dst[3] = ls1;
    }
    __syncthreads();   // e-table visible to all waves

    // ---- phase B: wave = 64-col slice, lane = 1 col, all 64 rows, 16 heads ----
    const int col = wv * 64 + l;
    const float* x3c = x3 + ((size_t)b * SS + s0) * DIN + col;
    float acc[16];
#pragma unroll
    for (int h = 0; h < 16; ++h) acc[h] = 0.f;

    float x0 = x3c[0];
    float x1 = x3c[DIN];
    float x2r = x3c[2 * DIN];
    float x3r = x3c[3 * DIN];
#pragma unroll 4
    for (int j = 0; j < 64; ++j) {
        const float xv = x0;
        x0 = x1; x1 = x2r; x2r = x3r;
        const int jn = (j + 4 < 64) ? (j + 4) : 63;
        x3r = x3c[(size_t)jn * DIN];
        const float4 ea = *(const float4*)&etab[j * 20];       // broadcast
        const float4 eb = *(const float4*)&etab[j * 20 + 4];
        const float4 ec = *(const float4*)&etab[j * 20 + 8];
        const float4 ed = *(const float4*)&etab[j * 20 + 12];
        acc[0]  += ea.x * xv;  acc[1]  += ea.y * xv;
        acc[2]  += ea.z * xv;  acc[3]  += ea.w * xv;
        acc[4]  += eb.x * xv;  acc[5]  += eb.y * xv;
        acc[6]  += eb.z * xv;  acc[7]  += eb.w * xv;
        acc[8]  += ec.x * xv;  acc[9]  += ec.y * xv;
        acc[10] += ec.z * xv;  acc[11] += ec.w * xv;
        acc[12] += ed.x * xv;  acc[13] += ed.y * xv;
        acc[14] += ed.z * xv;  acc[15] += ed.w * xv;
    }

    // epilogue: direct gp writes (wave's col slice of all 16 head rows)
    float* gb = gp + ((size_t)(b * NCH + ch) * NH) * DIN + col;
#pragma unroll
    for (int h = 0; h < 16; ++h)
        gb[(size_t)h * DIN] = acc[h];
}

// Flash combine: g[b*16+h][i] = sum_ch exp(m_ch-M)*gp_ch[i] / sum_ch exp(m_ch-M)*l_ch
// grid 512: blockIdx.x = pair*2 + half; thread owns one i-col.
__global__ __launch_bounds__(256) void k_greduce2(const float* __restrict__ gp,
                                                  const float* __restrict__ mls,
                                                  float* __restrict__ g) {
    const int bx = blockIdx.x;        // 512
    const int pair = bx >> 1;         // b*16+h
    const int b = pair >> 4, h = pair & 15;
    const int i = (bx & 1) * 256 + threadIdx.x;
    const float* mbase = mls + ((size_t)b * NCH * NH + h) * 2;  // stride NH*2/ch
    float M = -1e30f;
#pragma unroll 8
    for (int ch = 0; ch < NCH; ++ch)
        M = fmaxf(M, mbase[(size_t)ch * NH * 2]);   // uniform -> s_load
    float L = 0.f;
#pragma unroll 8
    for (int ch = 0; ch < NCH; ++ch)
        L += __expf(mbase[(size_t)ch * NH * 2] - M) * mbase[(size_t)ch * NH * 2 + 1];
    const float invL = 1.f / L;
    const float* gpb = gp + ((size_t)(b * NCH) * NH + h) * DIN + i;
    float acc = 0.f;
#pragma unroll 8
    for (int ch = 0; ch < NCH; ++ch)
        acc += __expf(mbase[(size_t)ch * NH * 2] - M) * gpb[(size_t)ch * NH * DIN];
    g[(size_t)pair * DIN + i] = acc * invL;
}

// av[b][h*64+l] (+)= sum_c G2[b*16+h][c]*Wv[c][h*64+l] over a 128-c chunk.
__global__ __launch_bounds__(256) void k_av_at(const float* __restrict__ G2,
                                               const float* __restrict__ Wv,
                                               float* __restrict__ av) {
    const int h = blockIdx.x;
    const int l = threadIdx.x & 63;
    const int wv = wave_id();
    const int c0 = blockIdx.y * 128 + wv * 32;
    float acc[16];
#pragma unroll
    for (int bb = 0; bb < 16; ++bb) acc[bb] = 0.f;
#pragma unroll 4
    for (int c = c0; c < c0 + 32; ++c) {
        const float wval = Wv[(size_t)c * DD + h * HD + l];  // coalesced
#pragma unroll
        for (int bb = 0; bb < 16; ++bb)
            acc[bb] += G2[((size_t)bb * NH + h) * DD + c] * wval;  // s_load
    }
    __shared__ float red[4][16][64];
#pragma unroll
    for (int bb = 0; bb < 16; ++bb) red[wv][bb][l] = acc[bb];
    __syncthreads();
#pragma unroll
    for (int k = 0; k < 4; ++k) {
        const int bb = wv + k * 4;
        float v = red[0][bb][l] + red[1][bb][l] + red[2][bb][l] + red[3][bb][l];
        atomicAdd(&av[(size_t)bb * DD + h * HD + l], v);
    }
}

extern "C" void kernel_launch(void* const* d_in, const int* in_sizes, int n_in,
                              void* d_out, int out_size, void* d_ws, size_t ws_size,
                              hipStream_t stream) {
    const float* x1  = (const float*)d_in[0];
    const float* x2  = (const float*)d_in[1];
    const float* x3  = (const float*)d_in[2];
    const float* We1 = (const float*)d_in[3];
    const float* be1 = (const float*)d_in[4];
    const float* We2 = (const float*)d_in[5];
    const float* be2 = (const float*)d_in[6];
    const float* Wq  = (const float*)d_in[7];
    const float* bq  = (const float*)d_in[8];
    const float* Wk  = (const float*)d_in[9];
    const float* bk  = (const float*)d_in[10];  // cancels in softmax (unused)
    const float* Wv  = (const float*)d_in[11];
    const float* bv  = (const float*)d_in[12];
    const float* Wo  = (const float*)d_in[13];
    const float* bo  = (const float*)d_in[14];
    (void)bk;
    float* out = (float*)d_out;

    char* ws = (char*)d_ws;
    size_t off = 0;
    auto alloc = [&](size_t bytes) -> void* {
        void* p = ws + off;
        off = (off + bytes + 255) & ~(size_t)255;
        return p;
    };
    float* We2t = (float*)alloc((size_t)DD * DIN * 4);  // [1024][512]
    float* WkT  = (float*)alloc((size_t)DD * DD * 4);   // [1024][1024]
    float* x1e  = (float*)alloc((size_t)BB * DD * 4);
    float* qb   = (float*)alloc((size_t)BB * DD * 4);
    float* u    = (float*)alloc((size_t)BB * NH * DD * 4);
    float* wv_  = (float*)alloc((size_t)BB * NH * DIN * 4);
    float* g    = (float*)alloc((size_t)BB * NH * DIN * 4);
    float* G2   = (float*)alloc((size_t)BB * NH * DD * 4);
    float* av   = (float*)alloc((size_t)BB * DD * 4);
    float* gp   = (float*)alloc((size_t)BB * NCH * NH * DIN * 4);  // 32MB
    float* mls  = (float*)alloc((size_t)BB * NCH * NH * 2 * 4);

    // prep: transposes + bias inits (one dispatch)
    k_prep<<<1552, 256, 0, stream>>>(We2, Wk, be1, bq, bv, bo,
                                     We2t, WkT, x1e, qb, av, out);
    // x1e += x1@We1   (K=512, KS=8 -> 128 blocks)
    k_bmv2<DIN, DD, 8, false><<<dim3(DD / 64, 1, 8), 256, 0, stream>>>(x1, We1, nullptr, x1e);
    // qb += x1e@Wq    (K=1024, KS=8 -> 128 blocks)
    k_bmv2<DD, DD, 8, false><<<dim3(DD / 64, 1, 8), 256, 0, stream>>>(x1e, Wq, nullptr, qb);
    k_u2<<<dim3(DD / 64, NH), 256, 0, stream>>>(qb, WkT, u);
    // w = u@We2t      (R=256 -> 128 blocks)
    k_bmv2<DD, DIN, 1, false><<<dim3(DIN / 64, BB * NH / 16, 1), 256, 0, stream>>>(u, We2t, nullptr, wv_);
    // fused scores + softmax + PV partials (1024 blocks x 8 waves = 32 waves/CU)
    k_attn<<<dim3(NCH, BB), 512, 0, stream>>>(x2, x3, wv_, gp, mls);
    k_greduce2<<<BB * NH * 2, 256, 0, stream>>>(gp, mls, g);
    // G2 = g@We2+be2  (R=256 -> 256 blocks)
    k_bmv2<DIN, DD, 1, true><<<dim3(DD / 64, BB * NH / 16, 1), 256, 0, stream>>>(g, We2, be2, G2);
    k_av_at<<<dim3(NH, 8), 256, 0, stream>>>(G2, Wv, av);
    // out += av@Wo    (K=1024, KS=8 -> 128 blocks)
    k_bmv2<DD, DD, 8, false><<<dim3(DD / 64, 1, 8), 256, 0, stream>>>(av, Wo, nullptr, out);
}

// Round 3
// 446.000 us; speedup vs baseline: 1.0153x; 1.0020x over previous
//
#include <hip/hip_runtime.h>

// CrossAttention decode, algebraically collapsed (all fp32):
//   q[b,h,:]   = ((x1@We1+be1)@Wq+bq) head-sliced
//   u[b,h,c]   = sum_d WkT[h*64+d,c]*q[b,h,d]
//   w[b,h,i]   = sum_c u[b,h,c]*We2t[c,i]          (K-proj folded)
//   score[b,h,s] = x2[b,s,:].w[b,h,:]              (K-bias cancels in softmax)
//   a = softmax(score/8)
//   g[b,h,i]   = sum_s a[b,h,s]*x3[b,s,i]
//   G2[b,h,c]  = g@We2 + be2;  av = G2@Wv_h + bv;  out = av@Wo + bo
// R3 (this round): R1/R2 showed occupancy 39->81% and 2x LDS-traffic changes
// leave k_attn at ~110us: not wave-latency-bound, not LDS/VALU-bound -> the
// cap is per-CU memory bytes-in-flight. Phase B used 4B/lane loads (256B/
// wave-instr, ~1KB in flight); copy ceiling needs 16B/lane (1KB/instr, 4KB
// in flight). Fix: phase B wave = (4-head group x 256-col half), lane owns
// 4 cols (float4 loads+stores), acc[4 heads]x4 cols, no cross-wave reduce;
// x3 instrs 4x redundant across head-groups but L1/L2-absorbed (HBM same).
// Phase A: reg-staged prefetch (issue kt+1 loads early, compute kt under
// them, ds_write late) hides staging latency under the FMA loop.
// Lessons kept: no per-element global atomics on hot paths; stride-33/pad-20
// LDS (16B-aligned, conflict-free); harness reset (~170us) fixed overhead.

#define DIN 512
#define DD  1024
#define NH  16
#define HD  64
#define BB  16
#define SS  4096
#define NCH 64   // s-chunks; schunk = 64

__device__ __forceinline__ int wave_id() {
    return __builtin_amdgcn_readfirstlane((int)(threadIdx.x >> 6));
}

__device__ __forceinline__ void tile_transpose(const float* __restrict__ in,
                                               float* __restrict__ out,
                                               int R, int C, int rblk, int cblk) {
    __shared__ float tl[32][33];
    const int tx = threadIdx.x & 31, ty = threadIdx.x >> 5;  // ty 0..7
    const int c0 = cblk * 32, r0 = rblk * 32;
#pragma unroll
    for (int k = 0; k < 4; ++k)
        tl[ty + k * 8][tx] = in[(size_t)(r0 + ty + k * 8) * C + c0 + tx];
    __syncthreads();
#pragma unroll
    for (int k = 0; k < 4; ++k)
        out[(size_t)(c0 + ty + k * 8) * R + r0 + tx] = tl[tx][ty + k * 8];
}

// One fused prep dispatch: We2/Wk transposes + bias init of atomic targets.
__global__ __launch_bounds__(256) void k_prep(const float* __restrict__ We2,
                                              const float* __restrict__ Wk,
                                              const float* __restrict__ be1,
                                              const float* __restrict__ bq,
                                              const float* __restrict__ bv,
                                              const float* __restrict__ bo,
                                              float* __restrict__ We2t,
                                              float* __restrict__ WkT,
                                              float* __restrict__ x1e,
                                              float* __restrict__ qb,
                                              float* __restrict__ av,
                                              float* __restrict__ out) {
    const int bx = blockIdx.x;
    if (bx < 512) {
        tile_transpose(We2, We2t, DIN, DD, bx >> 5, bx & 31);
    } else if (bx < 1536) {
        const int lb = bx - 512;
        tile_transpose(Wk, WkT, DD, DD, lb >> 5, lb & 31);
    } else {
        const int b = bx - 1536;
#pragma unroll
        for (int k = 0; k < 4; ++k) {
            const int c = k * 256 + threadIdx.x;
            x1e[(size_t)b * DD + c] = be1[c];
            qb[(size_t)b * DD + c]  = bq[c];
            av[(size_t)b * DD + c]  = bv[c];
            out[(size_t)b * DD + c] = bo[c];
        }
    }
}

// out[r][c] (+)= sum_i in[r][i]*W[i][c] for 16 rows. grid (N/64, R/16, KS).
template <int K, int N, int KS, bool HASB>
__global__ __launch_bounds__(256) void k_bmv2(const float* __restrict__ in,
                                              const float* __restrict__ W,
                                              const float* __restrict__ bias,
                                              float* __restrict__ out) {
    const int l = threadIdx.x & 63;
    const int c = blockIdx.x * 64 + l;
    const int wv = wave_id();
    constexpr int KCH = K / KS;
    constexpr int SUB = KCH / 4;
    const float* inb = in + (size_t)blockIdx.y * 16 * K;  // uniform -> s_load
    float acc[16];
#pragma unroll
    for (int r = 0; r < 16; ++r) acc[r] = 0.f;
    const int i0 = blockIdx.z * KCH + wv * SUB;
#pragma unroll 4
    for (int i = i0; i < i0 + SUB; ++i) {
        const float wval = W[(size_t)i * N + c];  // coalesced 256B/wave
#pragma unroll
        for (int r = 0; r < 16; ++r) acc[r] += inb[(size_t)r * K + i] * wval;
    }
    __shared__ float red[4][16][64];
#pragma unroll
    for (int r = 0; r < 16; ++r) red[wv][r][l] = acc[r];
    __syncthreads();
#pragma unroll
    for (int k = 0; k < 4; ++k) {
        const int r = wv + k * 4;
        float v = red[0][r][l] + red[1][r][l] + red[2][r][l] + red[3][r][l];
        float* dst = out + ((size_t)blockIdx.y * 16 + r) * N + c;
        if (KS == 1) {
            if (HASB) v += bias[c];
            *dst = v;
        } else {
            atomicAdd(dst, v);
        }
    }
}

// u[b*16+h][c] = sum_d q[b][h*64+d]*WkT[h*64+d][c].  grid (1024/64, 16 h).
__global__ __launch_bounds__(256) void k_u2(const float* __restrict__ q,
                                            const float* __restrict__ WkT,
                                            float* __restrict__ u) {
    const int h = blockIdx.y;
    const int l = threadIdx.x & 63;
    const int c = blockIdx.x * 64 + l;
    const int wv = wave_id();
    float acc[16];
#pragma unroll
    for (int bb = 0; bb < 16; ++bb) acc[bb] = 0.f;
#pragma unroll 4
    for (int dk = 0; dk < 16; ++dk) {
        const int d = wv * 16 + dk;
        const float wval = WkT[(size_t)(h * HD + d) * DD + c];  // coalesced
#pragma unroll
        for (int bb = 0; bb < 16; ++bb)
            acc[bb] += q[(size_t)bb * DD + h * HD + d] * wval;  // s_load
    }
    __shared__ float red[4][16][64];
#pragma unroll
    for (int bb = 0; bb < 16; ++bb) red[wv][bb][l] = acc[bb];
    __syncthreads();
#pragma unroll
    for (int k = 0; k < 4; ++k) {
        const int bb = wv + k * 4;
        float v = red[0][bb][l] + red[1][bb][l] + red[2][bb][l] + red[3][bb][l];
        u[((size_t)bb * NH + h) * DD + c] = v;
    }
}

// Fused scores+softmax+PV: grid (NCH=64, 16 b), block 512 (8 waves).
// Phase A: wave wv owns heads 2wv..2wv+1, lane = s-row; x2 reg-staged then
// ds_written (prefetch kt+1 issued before kt's compute -> latency hidden);
// per-head chunk max+sum via shfl-xor; e-values to pad-20 e-table; mls here.
// Phase B: wave wv = (head-group wv>>1 of 4 heads, col-half wv&1 of 256
// cols); lane owns 4 cols (float4). 64 rows, 4-deep float4 pipeline (4KB
// in flight/wave); e read as one broadcast float4/row; acc 4 heads x float4;
// disjoint (head,col) partition -> direct float4 gp stores, no reduce.
__global__ __launch_bounds__(512, 8) void k_attn(const float* __restrict__ x2,
                                                 const float* __restrict__ x3,
                                                 const float* __restrict__ w,
                                                 float* __restrict__ gp,
                                                 float* __restrict__ mls) {
    __shared__ __align__(16) float4 tile[64 * 33];  // 33.8 KB x2 stage
    __shared__ __align__(16) float etab[64 * 20];   // 5 KB e-table [row][head], pad 20

    const int b = blockIdx.y, ch = blockIdx.x;
    const int l = threadIdx.x & 63;
    const int wv = wave_id();          // 0..7
    const int h0 = wv * 2;
    const int s0 = ch * 64;
    const float4* wp = (const float4*)(w + ((size_t)b * NH + h0) * DIN);
    const float4* x2f = (const float4*)x2 + ((size_t)b * SS + s0) * (DIN / 4);

    // ---- phase A: scores for rows s0..s0+64, heads h0..h0+1 (lane = row) ----
    const int srow = threadIdx.x >> 5;   // 0..15 (staging row base)
    const int sc4  = threadIdx.x & 31;   // 0..31 (staging col)
    // prefetch kt=0 into registers
    float4 r0 = x2f[(size_t)(srow)      * 128 + sc4];
    float4 r1 = x2f[(size_t)(srow + 16) * 128 + sc4];
    float4 r2 = x2f[(size_t)(srow + 32) * 128 + sc4];
    float4 r3 = x2f[(size_t)(srow + 48) * 128 + sc4];
    float a0 = 0.f, a1 = 0.f;
    for (int kt = 0; kt < 4; ++kt) {
        __syncthreads();                    // prev compute done; tile free
        tile[(srow)      * 33 + sc4] = r0;  // vmcnt waits inserted here
        tile[(srow + 16) * 33 + sc4] = r1;
        tile[(srow + 32) * 33 + sc4] = r2;
        tile[(srow + 48) * 33 + sc4] = r3;
        __syncthreads();                    // tile ready
        if (kt < 3) {                       // issue kt+1 loads; land under compute
            const int kc = (kt + 1) * 32 + sc4;
            r0 = x2f[(size_t)(srow)      * 128 + kc];
            r1 = x2f[(size_t)(srow + 16) * 128 + kc];
            r2 = x2f[(size_t)(srow + 32) * 128 + kc];
            r3 = x2f[(size_t)(srow + 48) * 128 + kc];
        }
#pragma unroll 8
        for (int c4 = 0; c4 < 32; ++c4) {
            const float4 x = tile[l * 33 + c4];
            const float4 q0 = wp[kt * 32 + c4];            // uniform -> s_load
            const float4 q1 = wp[128 + kt * 32 + c4];
            a0 += x.x * q0.x + x.y * q0.y + x.z * q0.z + x.w * q0.w;
            a1 += x.x * q1.x + x.y * q1.y + x.z * q1.z + x.w * q1.w;
        }
    }

    // per-head chunk max + e + sum, all in-wave (lane = row)
    const float sc0 = a0 * 0.125f, sc1 = a1 * 0.125f;
    float m0 = sc0, m1 = sc1;
#pragma unroll
    for (int off = 1; off < 64; off <<= 1) {
        m0 = fmaxf(m0, __shfl_xor(m0, off));
        m1 = fmaxf(m1, __shfl_xor(m1, off));
    }
    const float e0 = __expf(sc0 - m0), e1 = __expf(sc1 - m1);
    etab[l * 20 + h0]     = e0;
    etab[l * 20 + h0 + 1] = e1;
    float ls0 = e0, ls1 = e1;
#pragma unroll
    for (int off = 1; off < 64; off <<= 1) {
        ls0 += __shfl_xor(ls0, off);
        ls1 += __shfl_xor(ls1, off);
    }
    if (l == 0) {
        float* dst = mls + (((size_t)b * NCH + ch) * NH + h0) * 2;
        dst[0] = m0; dst[1] = ls0;
        dst[2] = m1; dst[3] = ls1;
    }
    __syncthreads();   // e-table visible to all waves

    // ---- phase B: wave = (4-head group, 256-col half), lane = 4 cols ----
    const int colh = wv & 1;           // col half: 0,1
    const int h4 = (wv >> 1) * 4;      // head group base: 0,4,8,12
    const float4* x3f = (const float4*)(x3 + ((size_t)b * SS + s0) * DIN)
                        + colh * 64 + l;
    float4 A0 = make_float4(0.f, 0.f, 0.f, 0.f);
    float4 A1 = make_float4(0.f, 0.f, 0.f, 0.f);
    float4 A2 = make_float4(0.f, 0.f, 0.f, 0.f);
    float4 A3 = make_float4(0.f, 0.f, 0.f, 0.f);

    float4 p0 = x3f[0 * 128], p1 = x3f[1 * 128];
    float4 p2 = x3f[2 * 128], p3 = x3f[3 * 128];
#pragma unroll 4
    for (int j = 0; j < 64; ++j) {
        const float4 xv = p0;
        p0 = p1; p1 = p2; p2 = p3;
        const int jn = (j + 4 < 64) ? (j + 4) : 63;
        p3 = x3f[(size_t)jn * 128];
        const float4 e4 = *(const float4*)&etab[j * 20 + h4];  // broadcast
        A0.x += e4.x * xv.x; A0.y += e4.x * xv.y; A0.z += e4.x * xv.z; A0.w += e4.x * xv.w;
        A1.x += e4.y * xv.x; A1.y += e4.y * xv.y; A1.z += e4.y * xv.z; A1.w += e4.y * xv.w;
        A2.x += e4.z * xv.x; A2.y += e4.z * xv.y; A2.z += e4.z * xv.z; A2.w += e4.z * xv.w;
        A3.x += e4.w * xv.x; A3.y += e4.w * xv.y; A3.z += e4.w * xv.z; A3.w += e4.w * xv.w;
    }

    // epilogue: direct float4 gp stores (disjoint head x col partition)
    float* gb = gp + ((size_t)(b * NCH + ch) * NH + h4) * DIN + colh * 256 + 4 * l;
    *(float4*)(gb + 0 * DIN) = A0;
    *(float4*)(gb + 1 * DIN) = A1;
    *(float4*)(gb + 2 * DIN) = A2;
    *(float4*)(gb + 3 * DIN) = A3;
}

// Flash combine: g[b*16+h][i] = sum_ch exp(m_ch-M)*gp_ch[i] / sum_ch exp(m_ch-M)*l_ch
// grid 512: blockIdx.x = pair*2 + half; thread owns one i-col.
__global__ __launch_bounds__(256) void k_greduce2(const float* __restrict__ gp,
                                                  const float* __restrict__ mls,
                                                  float* __restrict__ g) {
    const int bx = blockIdx.x;        // 512
    const int pair = bx >> 1;         // b*16+h
    const int b = pair >> 4, h = pair & 15;
    const int i = (bx & 1) * 256 + threadIdx.x;
    const float* mbase = mls + ((size_t)b * NCH * NH + h) * 2;  // stride NH*2/ch
    float M = -1e30f;
#pragma unroll 8
    for (int ch = 0; ch < NCH; ++ch)
        M = fmaxf(M, mbase[(size_t)ch * NH * 2]);   // uniform -> s_load
    float L = 0.f;
#pragma unroll 8
    for (int ch = 0; ch < NCH; ++ch)
        L += __expf(mbase[(size_t)ch * NH * 2] - M) * mbase[(size_t)ch * NH * 2 + 1];
    const float invL = 1.f / L;
    const float* gpb = gp + ((size_t)(b * NCH) * NH + h) * DIN + i;
    float acc = 0.f;
#pragma unroll 8
    for (int ch = 0; ch < NCH; ++ch)
        acc += __expf(mbase[(size_t)ch * NH * 2] - M) * gpb[(size_t)ch * NH * DIN];
    g[(size_t)pair * DIN + i] = acc * invL;
}

// av[b][h*64+l] (+)= sum_c G2[b*16+h][c]*Wv[c][h*64+l] over a 128-c chunk.
__global__ __launch_bounds__(256) void k_av_at(const float* __restrict__ G2,
                                               const float* __restrict__ Wv,
                                               float* __restrict__ av) {
    const int h = blockIdx.x;
    const int l = threadIdx.x & 63;
    const int wv = wave_id();
    const int c0 = blockIdx.y * 128 + wv * 32;
    float acc[16];
#pragma unroll
    for (int bb = 0; bb < 16; ++bb) acc[bb] = 0.f;
#pragma unroll 4
    for (int c = c0; c < c0 + 32; ++c) {
        const float wval = Wv[(size_t)c * DD + h * HD + l];  // coalesced
#pragma unroll
        for (int bb = 0; bb < 16; ++bb)
            acc[bb] += G2[((size_t)bb * NH + h) * DD + c] * wval;  // s_load
    }
    __shared__ float red[4][16][64];
#pragma unroll
    for (int bb = 0; bb < 16; ++bb) red[wv][bb][l] = acc[bb];
    __syncthreads();
#pragma unroll
    for (int k = 0; k < 4; ++k) {
        const int bb = wv + k * 4;
        float v = red[0][bb][l] + red[1][bb][l] + red[2][bb][l] + red[3][bb][l];
        atomicAdd(&av[(size_t)bb * DD + h * HD + l], v);
    }
}

extern "C" void kernel_launch(void* const* d_in, const int* in_sizes, int n_in,
                              void* d_out, int out_size, void* d_ws, size_t ws_size,
                              hipStream_t stream) {
    const float* x1  = (const float*)d_in[0];
    const float* x2  = (const float*)d_in[1];
    const float* x3  = (const float*)d_in[2];
    const float* We1 = (const float*)d_in[3];
    const float* be1 = (const float*)d_in[4];
    const float* We2 = (const float*)d_in[5];
    const float* be2 = (const float*)d_in[6];
    const float* Wq  = (const float*)d_in[7];
    const float* bq  = (const float*)d_in[8];
    const float* Wk  = (const float*)d_in[9];
    const float* bk  = (const float*)d_in[10];  // cancels in softmax (unused)
    const float* Wv  = (const float*)d_in[11];
    const float* bv  = (const float*)d_in[12];
    const float* Wo  = (const float*)d_in[13];
    const float* bo  = (const float*)d_in[14];
    (void)bk;
    float* out = (float*)d_out;

    char* ws = (char*)d_ws;
    size_t off = 0;
    auto alloc = [&](size_t bytes) -> void* {
        void* p = ws + off;
        off = (off + bytes + 255) & ~(size_t)255;
        return p;
    };
    float* We2t = (float*)alloc((size_t)DD * DIN * 4);  // [1024][512]
    float* WkT  = (float*)alloc((size_t)DD * DD * 4);   // [1024][1024]
    float* x1e  = (float*)alloc((size_t)BB * DD * 4);
    float* qb   = (float*)alloc((size_t)BB * DD * 4);
    float* u    = (float*)alloc((size_t)BB * NH * DD * 4);
    float* wv_  = (float*)alloc((size_t)BB * NH * DIN * 4);
    float* g    = (float*)alloc((size_t)BB * NH * DIN * 4);
    float* G2   = (float*)alloc((size_t)BB * NH * DD * 4);
    float* av   = (float*)alloc((size_t)BB * DD * 4);
    float* gp   = (float*)alloc((size_t)BB * NCH * NH * DIN * 4);  // 32MB
    float* mls  = (float*)alloc((size_t)BB * NCH * NH * 2 * 4);

    // prep: transposes + bias inits (one dispatch)
    k_prep<<<1552, 256, 0, stream>>>(We2, Wk, be1, bq, bv, bo,
                                     We2t, WkT, x1e, qb, av, out);
    // x1e += x1@We1   (K=512, KS=8 -> 128 blocks)
    k_bmv2<DIN, DD, 8, false><<<dim3(DD / 64, 1, 8), 256, 0, stream>>>(x1, We1, nullptr, x1e);
    // qb += x1e@Wq    (K=1024, KS=8 -> 128 blocks)
    k_bmv2<DD, DD, 8, false><<<dim3(DD / 64, 1, 8), 256, 0, stream>>>(x1e, Wq, nullptr, qb);
    k_u2<<<dim3(DD / 64, NH), 256, 0, stream>>>(qb, WkT, u);
    // w = u@We2t      (R=256 -> 128 blocks)
    k_bmv2<DD, DIN, 1, false><<<dim3(DIN / 64, BB * NH / 16, 1), 256, 0, stream>>>(u, We2t, nullptr, wv_);
    // fused scores + softmax + PV partials (1024 blocks x 8 waves = 32 waves/CU)
    k_attn<<<dim3(NCH, BB), 512, 0, stream>>>(x2, x3, wv_, gp, mls);
    k_greduce2<<<BB * NH * 2, 256, 0, stream>>>(gp, mls, g);
    // G2 = g@We2+be2  (R=256 -> 256 blocks)
    k_bmv2<DIN, DD, 1, true><<<dim3(DD / 64, BB * NH / 16, 1), 256, 0, stream>>>(g, We2, be2, G2);
    k_av_at<<<dim3(NH, 8), 256, 0, stream>>>(G2, Wv, av);
    // out += av@Wo    (K=1024, KS=8 -> 128 blocks)
    k_bmv2<DD, DD, 8, false><<<dim3(DD / 64, 1, 8), 256, 0, stream>>>(av, Wo, nullptr, out);
}